// Round 5
// baseline (1501.491 us; speedup 1.0000x reference)
//
#include <hip/hip_runtime.h>
#include <math.h>

// GCN 2-layer (1->8->1), collapsed + factored, SRC-sorted + fire-and-forget
// global atomics (no gathers on the critical path).
//
// Math (verified):
//   deg[d]  = #edges into d; dinv = rsqrt(deg+1)            (self-loop)
//   v[i]    = dinv[i]*x[i]                                  (stored fp16)
//   acc1[d] = sum_e v[src[e]]
//   at[i]   = dinv[i]*(acc1[i] + v[i])
//   u[i]    = dinv[i] * sum_j relu(at[i]*W1[j]+b1[j])*W2[j] (stored fp16)
//   out[d]  = dinv[d]*(acc2[d] + u[d]) + b2,  acc2[d] = sum_e u[src[e]]
//
// Round-18: r14 (TLP), r15 (ILP), r16/r17 (LDS-sliced gather) all converge to
// ~4-5 cy/edge/CU because each keeps a data-dependent LOAD (gather) on the
// wave's critical path. This round removes the gather: sort by SRC-window
// (4096 nodes; rec = (srcoff12<<20)|dst20), stage the 8KB v-window in LDS
// once per block, and make the per-edge random op a fire-and-forget
// atomicAdd(&acc[dst], val) -- no return value, nothing on the critical
// path. deg comes from a raw streaming pass over dst with int atomics
// (replaces the 55us record-based k_degv). k_gs: 8KB LDS, 256 thr,
// grid 245*8 -> high occupancy.

typedef int vint4 __attribute__((ext_vector_type(4)));

#define DSH    12        // src-window shift (4096 nodes)
#define DW     4096
#define NWMAX  256       // max windows (N <= 2^20)
#define STHR   1024      // sort block size
#define CHUNK  16384     // edges per sort block
#define SSPLIT 8         // sub-blocks per window in k_gs

// ---- zero deg/acc1/acc2/gcur (contiguous) ----
__global__ void k_zero(int* __restrict__ p, long n) {
    long i = blockIdx.x * (long)blockDim.x + threadIdx.x;
    long stride = (long)gridDim.x * blockDim.x;
    long n4 = n >> 2;
    vint4* p4 = reinterpret_cast<vint4*>(p);
    for (long k = i; k < n4; k += stride) p4[k] = (vint4){0, 0, 0, 0};
    for (long k = (n4 << 2) + i; k < n; k += stride) p[k] = 0;
}

// ---- deg: raw dst stream + fire-and-forget int atomics ----
__global__ __launch_bounds__(256) void k_deg(const int* __restrict__ dst, int E,
                                             int* __restrict__ deg) {
    int n4 = E >> 2;
    int stride = gridDim.x * blockDim.x;
    int i0 = blockIdx.x * blockDim.x + threadIdx.x;
    const vint4* pd = reinterpret_cast<const vint4*>(dst);
    for (int k = i0; k < n4; k += stride) {
        vint4 d = __builtin_nontemporal_load(pd + k);
        atomicAdd(&deg[d.x], 1);
        atomicAdd(&deg[d.y], 1);
        atomicAdd(&deg[d.z], 1);
        atomicAdd(&deg[d.w], 1);
    }
    for (int k = (n4 << 2) + i0; k < E; k += stride)
        atomicAdd(&deg[__builtin_nontemporal_load(dst + k)], 1);
}

// ---- counting sort by src-window; rec = (srcoff12 << 20) | dst20 ----
__global__ __launch_bounds__(STHR) void k_sort(const int* __restrict__ src,
                                               const int* __restrict__ dst,
                                               int E, int NW, int C,
                                               int* __restrict__ gcur,
                                               int* __restrict__ recs) {
    __shared__ int cnt[NWMAX];             // A: counts; C: cursors
    __shared__ int res[NWMAX];
    __shared__ int part[STHR];
    __shared__ int stage[CHUNK];           // 64 KB window-ordered staging
    __shared__ unsigned char s2b[CHUNK];   // 16 KB slot -> window

    int t = threadIdx.x;
    if (t < NWMAX) cnt[t] = 0;
    __syncthreads();

    long s0 = (long)blockIdx.x * CHUNK;
    long rem = (long)E - s0;
    int end = (int)(rem < CHUNK ? rem : CHUNK);
    const vint4* ps = reinterpret_cast<const vint4*>(src + s0);
    const vint4* pd = reinterpret_cast<const vint4*>(dst + s0);
    int n4 = end >> 2;

    // phase A: histogram over src (plain loads keep lines in L2 for phase C)
    for (int k = t; k < n4; k += STHR) {
        vint4 s = ps[k];
        atomicAdd(&cnt[((unsigned)s.x) >> DSH], 1);
        atomicAdd(&cnt[((unsigned)s.y) >> DSH], 1);
        atomicAdd(&cnt[((unsigned)s.z) >> DSH], 1);
        atomicAdd(&cnt[((unsigned)s.w) >> DSH], 1);
    }
    for (int k = (n4 << 2) + t; k < end; k += STHR)
        atomicAdd(&cnt[((unsigned)src[s0 + k]) >> DSH], 1);
    __syncthreads();

    // phase B: block scan (1 window/thread; NW <= NWMAX <= STHR) + reservation
    int c0 = (t < NW) ? cnt[t] : 0;
    part[t] = c0;
    __syncthreads();
    for (int o = 1; o < STHR; o <<= 1) {
        int pv = (t >= o) ? part[t - o] : 0;
        __syncthreads();
        part[t] += pv;
        __syncthreads();
    }
    int base0 = (t > 0) ? part[t - 1] : 0;
    if (t < NW) {
        cnt[t] = base0;                    // cursor for phase C
        int r0 = c0 ? atomicAdd(&gcur[t], c0) : 0;
        res[t] = t * C + r0 - base0;
    }
    __syncthreads();

    // phase C: place records into LDS staging (window-ordered)
    for (int k = t; k < n4; k += STHR) {
        vint4 s = ps[k];
        vint4 d = __builtin_nontemporal_load(pd + k);
        int b, slot;
        b = ((unsigned)s.x) >> DSH; slot = atomicAdd(&cnt[b], 1);
        stage[slot] = ((s.x & (DW - 1)) << 20) | d.x; s2b[slot] = (unsigned char)b;
        b = ((unsigned)s.y) >> DSH; slot = atomicAdd(&cnt[b], 1);
        stage[slot] = ((s.y & (DW - 1)) << 20) | d.y; s2b[slot] = (unsigned char)b;
        b = ((unsigned)s.z) >> DSH; slot = atomicAdd(&cnt[b], 1);
        stage[slot] = ((s.z & (DW - 1)) << 20) | d.z; s2b[slot] = (unsigned char)b;
        b = ((unsigned)s.w) >> DSH; slot = atomicAdd(&cnt[b], 1);
        stage[slot] = ((s.w & (DW - 1)) << 20) | d.w; s2b[slot] = (unsigned char)b;
    }
    for (int k = (n4 << 2) + t; k < end; k += STHR) {
        int s = src[s0 + k], d = dst[s0 + k];
        int b = ((unsigned)s) >> DSH;
        int slot = atomicAdd(&cnt[b], 1);
        stage[slot] = ((s & (DW - 1)) << 20) | d;
        s2b[slot] = (unsigned char)b;
    }
    __syncthreads();

    // phase D: flush; long per-window runs -> L2-merged writes
    for (int i = t; i < end; i += STHR)
        recs[(long)res[s2b[i]] + i] = stage[i];
}

// ---- dinv = rsqrt(deg+1); v = dinv*x (fp16) ----
__global__ __launch_bounds__(256) void k_dinv(const int* __restrict__ deg,
                                              const float* __restrict__ x,
                                              float* __restrict__ dinv,
                                              _Float16* __restrict__ v, int N) {
    int i = blockIdx.x * blockDim.x + threadIdx.x;
    if (i < N) {
        float di = rsqrtf((float)deg[i] + 1.0f);
        dinv[i] = di;
        v[i] = (_Float16)(di * x[i]);
    }
}

// ---- scatter pass: LDS-staged src-window values + fire-and-forget atomics ----
__global__ __launch_bounds__(256) void k_gs(const int* __restrict__ recs,
                                            const int* __restrict__ gcur, int C,
                                            const _Float16* __restrict__ val,
                                            float* __restrict__ acc) {
    __shared__ _Float16 sl[DW];            // 8 KB src-window values
    int t = threadIdx.x;
    int w = blockIdx.x / SSPLIT, s = blockIdx.x % SSPLIT;
    const vint4* vw = reinterpret_cast<const vint4*>(val + (long)w * DW);
#pragma unroll
    for (int i = 0; i < 2; ++i)            // 512 vint4 / 256 threads
        ((vint4*)sl)[i * 256 + t] = vw[i * 256 + t];
    __syncthreads();
    long lo = (long)w * C;
    int cnt_w = gcur[w];
    int n4 = cnt_w >> 2;
    int q0 = (int)((long)n4 * s / SSPLIT);
    int q1 = (int)((long)n4 * (s + 1) / SSPLIT);
    const vint4* p = reinterpret_cast<const vint4*>(recs + lo);
    for (int k = q0 + t; k < q1; k += 256) {
        vint4 r = __builtin_nontemporal_load(p + k);
        float a0 = (float)sl[((unsigned)r.x) >> 20];
        float a1 = (float)sl[((unsigned)r.y) >> 20];
        float a2 = (float)sl[((unsigned)r.z) >> 20];
        float a3 = (float)sl[((unsigned)r.w) >> 20];
        atomicAdd(&acc[r.x & 0xFFFFF], a0);
        atomicAdd(&acc[r.y & 0xFFFFF], a1);
        atomicAdd(&acc[r.z & 0xFFFFF], a2);
        atomicAdd(&acc[r.w & 0xFFFFF], a3);
    }
    if (s == SSPLIT - 1) {
        for (int k = (n4 << 2) + t; k < cnt_w; k += 256) {
            int r = __builtin_nontemporal_load(recs + lo + k);
            atomicAdd(&acc[r & 0xFFFFF], (float)sl[((unsigned)r) >> 20]);
        }
    }
}

// ---- layer-1 epilogue: fused MLP -> u (fp16) ----
__global__ __launch_bounds__(256) void k_u(const float* __restrict__ acc1,
                                           const float* __restrict__ dinv,
                                           const _Float16* __restrict__ v,
                                           const float* __restrict__ W1,
                                           const float* __restrict__ b1,
                                           const float* __restrict__ W2,
                                           _Float16* __restrict__ u, int N) {
    int i = blockIdx.x * blockDim.x + threadIdx.x;
    if (i < N) {
        float di = dinv[i];
        float at = di * (acc1[i] + (float)v[i]);
        float ss = 0.0f;
#pragma unroll
        for (int jj = 0; jj < 8; ++jj)
            ss += fmaxf(at * W1[jj] + b1[jj], 0.0f) * W2[jj];
        u[i] = (_Float16)(di * ss);
    }
}

// ---- layer-2 epilogue: finalize ----
__global__ __launch_bounds__(256) void k_out(const float* __restrict__ acc2,
                                             const float* __restrict__ dinv,
                                             const _Float16* __restrict__ u,
                                             const float* __restrict__ b2,
                                             float* __restrict__ out, int N) {
    int i = blockIdx.x * blockDim.x + threadIdx.x;
    if (i < N)
        out[i] = dinv[i] * (acc2[i] + (float)u[i]) + b2[0];
}

extern "C" void kernel_launch(void* const* d_in, const int* in_sizes, int n_in,
                              void* d_out, int out_size, void* d_ws, size_t ws_size,
                              hipStream_t stream) {
    const float* x  = (const float*)d_in[0];
    const int*   ei = (const int*)d_in[1];   // [2, E] int32
    const float* W1 = (const float*)d_in[2];
    const float* b1 = (const float*)d_in[3];
    const float* W2 = (const float*)d_in[4];
    const float* b2 = (const float*)d_in[5];
    float* out = (float*)d_out;

    int N = in_sizes[0];
    int E = in_sizes[1] / 2;
    const int* src = ei;
    const int* dst = ei + E;

    int NW = (N + DW - 1) >> DSH;        // src-windows (245 for N=1e6)
    int NWP = (NW + 63) & ~63;           // padded for alignment

    // window capacity: avg + 8 sigma (Poisson), rounded to 64
    int avg = E / NW;
    int C = avg + 8 * (int)sqrt((double)avg) + 64;
    C = (C + 63) & ~63;
    size_t fixed = 8ul * (size_t)N               // dinv(4) + v(2) + u(2)
                 + 12ul * (size_t)N              // deg + acc1 + acc2
                 + sizeof(int) * (size_t)NWP;    // gcur
    size_t maxC = (ws_size - fixed) / (sizeof(int) * (size_t)NW);
    if ((size_t)C > maxC) C = (int)(maxC & ~63ul);

    char* w = (char*)d_ws;
    float*    dinv = (float*)w;     w += sizeof(float) * (size_t)N;
    _Float16* v    = (_Float16*)w;  w += sizeof(_Float16) * (size_t)N;
    _Float16* u    = (_Float16*)w;  w += sizeof(_Float16) * (size_t)N;
    int*      deg  = (int*)w;       w += sizeof(int) * (size_t)N;    // zeroed
    float*    acc1 = (float*)w;     w += sizeof(float) * (size_t)N;  // zeroed
    float*    acc2 = (float*)w;     w += sizeof(float) * (size_t)N;  // zeroed
    int*      gcur = (int*)w;       w += sizeof(int) * (size_t)NWP;  // zeroed
    int*      recs = (int*)w;       // NW * C ints

    int NBLK = (E + CHUNK - 1) / CHUNK;
    long zn = 3L * N + NWP;              // deg, acc1, acc2, gcur contiguous

    k_zero<<<1024, 256, 0, stream>>>(deg, zn);
    k_deg <<<2048, 256, 0, stream>>>(dst, E, deg);
    k_sort<<<NBLK, STHR, 0, stream>>>(src, dst, E, NW, C, gcur, recs);
    k_dinv<<<(N + 255) / 256, 256, 0, stream>>>(deg, x, dinv, v, N);
    k_gs  <<<NW * SSPLIT, 256, 0, stream>>>(recs, gcur, C, v, acc1);
    k_u   <<<(N + 255) / 256, 256, 0, stream>>>(acc1, dinv, v, W1, b1, W2, u, N);
    k_gs  <<<NW * SSPLIT, 256, 0, stream>>>(recs, gcur, C, u, acc2);
    k_out <<<(N + 255) / 256, 256, 0, stream>>>(acc2, dinv, u, b2, out, N);
}

// Round 6
// 440.717 us; speedup vs baseline: 3.4069x; 3.4069x over previous
//
#include <hip/hip_runtime.h>
#include <math.h>

// GCN 2-layer (1->8->1), collapsed + factored + two-level (dst-window 4096 x
// src-slice 16384) with ALL random accesses confined to LDS.
//
// Math (verified):
//   deg[d]  = #edges into d; dinv = rsqrt(deg+1)            (self-loop)
//   v[i]    = dinv[i]*x[i]                                  (stored fp16)
//   acc1[d] = sum_e v[src[e]]
//   at[i]   = dinv[i]*(acc1[i] + v[i])
//   u[i]    = dinv[i] * sum_j relu(at[i]*W1[j]+b1[j])*W2[j] (stored fp16)
//   out[d]  = dinv[d]*(acc2[d] + u[d]) + b2,  acc2[d] = sum_e u[src[e]]
//
// Evidence so far: 10M random op cost: LDS atomic (cheap) << global gather
// (70us, L1-MSHR-limited; occupancy-invariant per r14) << global atomic
// (483us, L2 line-RMW + 312MB writeback, r5). r4's LDS-sliced design failed
// only on occupancy (147KB LDS -> 1 blk/CU). This round keeps r4's structure
// at 80KB LDS (acc 16KB + 2x32KB fp16 slice dbuf) -> 2 blk/CU, grid 245x2
// (halves split the 62 src-slices; staging total stays 490MB, L2-resident).
// Per edge: coalesced rec load + ds_read_u16 + fire-and-forget LDS atomic.
// Exact record offsets via window-count prepass -> recs1+recs2 = 80MB exact;
// total ws = 90.1MB < 91.3MB proven. deg/dinv/v folded into sort2.
// rec1 = (dstoff12 << 20) | src20;  rec2 = (dstoff12 << 14) | srcoff14.

typedef int vint4 __attribute__((ext_vector_type(4)));

#define DSH   12        // dst-window shift (4096 nodes)
#define DW    4096
#define SSH   14        // src-slice shift (16384 nodes)
#define SW    16384
#define NWMAX 256       // max dst-windows (N <= 2^20)
#define STHR  1024      // sort1 block size
#define CHUNK 12288     // edges per sort1 block (65KB LDS -> 2 blk/CU)
#define CELLS 64        // boff stride (NSB+1 <= 64)
#define GTHR  512       // gs block size

__global__ void k_zero(int* __restrict__ p, long n) {
    long i = blockIdx.x * (long)blockDim.x + threadIdx.x;
    long stride = (long)gridDim.x * blockDim.x;
    long n4 = n >> 2;
    vint4* p4 = reinterpret_cast<vint4*>(p);
    for (long k = i; k < n4; k += stride) p4[k] = (vint4){0, 0, 0, 0};
    for (long k = (n4 << 2) + i; k < n; k += stride) p[k] = 0;
}

// ---- prepass: exact per-window edge counts ----
__global__ __launch_bounds__(256) void k_wcnt(const int* __restrict__ dst, int E,
                                              int NW, int* __restrict__ wcnt) {
    __shared__ int h[NWMAX];
    int t = threadIdx.x;
    h[t] = 0;
    if (t + 256 < NWMAX) h[t + 256] = 0;
    __syncthreads();
    const vint4* pd = reinterpret_cast<const vint4*>(dst);
    int n4 = E >> 2;
    int stride = gridDim.x * blockDim.x;
    for (int k = blockIdx.x * 256 + t; k < n4; k += stride) {
        vint4 d = __builtin_nontemporal_load(pd + k);
        atomicAdd(&h[((unsigned)d.x) >> DSH], 1);
        atomicAdd(&h[((unsigned)d.y) >> DSH], 1);
        atomicAdd(&h[((unsigned)d.z) >> DSH], 1);
        atomicAdd(&h[((unsigned)d.w) >> DSH], 1);
    }
    for (int k = (n4 << 2) + blockIdx.x * 256 + t; k < E; k += stride)
        atomicAdd(&h[((unsigned)dst[k]) >> DSH], 1);
    __syncthreads();
    for (int i = t; i < NW; i += 256)
        if (h[i]) atomicAdd(&wcnt[i], h[i]);
}

// ---- prepass: exclusive scan of window counts (single block) ----
__global__ __launch_bounds__(256) void k_wscan(const int* __restrict__ wcnt,
                                               int NW, int E,
                                               int* __restrict__ woff) {
    __shared__ int part[256];
    int t = threadIdx.x;
    int c = (t < NW) ? wcnt[t] : 0;
    part[t] = c;
    __syncthreads();
    for (int o = 1; o < 256; o <<= 1) {
        int pv = (t >= o) ? part[t - o] : 0;
        __syncthreads();
        part[t] += pv;
        __syncthreads();
    }
    if (t < NW) woff[t] = part[t] - c;
    if (t == NW - 1) woff[NW] = part[t];   // == E
}

// ---- pass 1: counting sort by dst-window into exact segments ----
__global__ __launch_bounds__(STHR) void k_sort1(const int* __restrict__ src,
                                                const int* __restrict__ dst,
                                                int E, int NW,
                                                const int* __restrict__ woff,
                                                int* __restrict__ gcur,
                                                int* __restrict__ recs) {
    __shared__ int cnt[NWMAX];             // A: counts; C: cursors
    __shared__ int res[NWMAX];
    __shared__ int part[STHR];
    __shared__ int stage[CHUNK];           // 48 KB window-ordered staging
    __shared__ unsigned char s2b[CHUNK];   // 12 KB slot -> window

    int t = threadIdx.x;
    if (t < NWMAX) cnt[t] = 0;
    __syncthreads();

    long s0 = (long)blockIdx.x * CHUNK;
    long rem = (long)E - s0;
    int end = (int)(rem < CHUNK ? rem : CHUNK);
    const vint4* pd = reinterpret_cast<const vint4*>(dst + s0);
    const vint4* ps = reinterpret_cast<const vint4*>(src + s0);
    int n4 = end >> 2;

    // phase A: histogram over dst (plain loads keep lines in L2 for phase C)
    for (int k = t; k < n4; k += STHR) {
        vint4 d = pd[k];
        atomicAdd(&cnt[((unsigned)d.x) >> DSH], 1);
        atomicAdd(&cnt[((unsigned)d.y) >> DSH], 1);
        atomicAdd(&cnt[((unsigned)d.z) >> DSH], 1);
        atomicAdd(&cnt[((unsigned)d.w) >> DSH], 1);
    }
    for (int k = (n4 << 2) + t; k < end; k += STHR)
        atomicAdd(&cnt[((unsigned)dst[s0 + k]) >> DSH], 1);
    __syncthreads();

    // phase B: block scan + global reservation into exact segment
    int c0 = (t < NW) ? cnt[t] : 0;
    part[t] = c0;
    __syncthreads();
    for (int o = 1; o < STHR; o <<= 1) {
        int pv = (t >= o) ? part[t - o] : 0;
        __syncthreads();
        part[t] += pv;
        __syncthreads();
    }
    int base0 = (t > 0) ? part[t - 1] : 0;
    if (t < NW) {
        cnt[t] = base0;                    // cursor for phase C
        int r0 = c0 ? atomicAdd(&gcur[t], c0) : 0;
        res[t] = woff[t] + r0 - base0;
    }
    __syncthreads();

    // phase C: place records into LDS staging (window-ordered)
    for (int k = t; k < n4; k += STHR) {
        vint4 d = pd[k];
        vint4 s = __builtin_nontemporal_load(ps + k);
        int b, slot;
        b = ((unsigned)d.x) >> DSH; slot = atomicAdd(&cnt[b], 1);
        stage[slot] = ((d.x & (DW - 1)) << 20) | s.x; s2b[slot] = (unsigned char)b;
        b = ((unsigned)d.y) >> DSH; slot = atomicAdd(&cnt[b], 1);
        stage[slot] = ((d.y & (DW - 1)) << 20) | s.y; s2b[slot] = (unsigned char)b;
        b = ((unsigned)d.z) >> DSH; slot = atomicAdd(&cnt[b], 1);
        stage[slot] = ((d.z & (DW - 1)) << 20) | s.z; s2b[slot] = (unsigned char)b;
        b = ((unsigned)d.w) >> DSH; slot = atomicAdd(&cnt[b], 1);
        stage[slot] = ((d.w & (DW - 1)) << 20) | s.w; s2b[slot] = (unsigned char)b;
    }
    for (int k = (n4 << 2) + t; k < end; k += STHR) {
        int d = dst[s0 + k], s = src[s0 + k];
        int b = ((unsigned)d) >> DSH;
        int slot = atomicAdd(&cnt[b], 1);
        stage[slot] = ((d & (DW - 1)) << 20) | s;
        s2b[slot] = (unsigned char)b;
    }
    __syncthreads();

    // phase D: flush; long per-window runs -> L2-merged writes
    for (int i = t; i < end; i += STHR)
        recs[(long)res[s2b[i]] + i] = stage[i];
}

// ---- pass 2: per-window src-slice binning + deg + dinv + v (fused) ----
__global__ __launch_bounds__(1024) void k_sort2(const int* __restrict__ recs1,
                                                const int* __restrict__ woff,
                                                const float* __restrict__ x,
                                                int NSB,
                                                int* __restrict__ recs2,
                                                int* __restrict__ boff,
                                                unsigned short* __restrict__ deg16,
                                                _Float16* __restrict__ v, int N) {
    __shared__ int degc[DW];           // 16 KB
    __shared__ int hw[16][CELLS];      // 4 KB wave-private slice histograms
    __shared__ int cnt_s[CELLS];
    __shared__ int cur[CELLS];
    int t = threadIdx.x, w = blockIdx.x, wid = t >> 6;
    for (int i = t; i < DW; i += 1024) degc[i] = 0;
    for (int i = t; i < 16 * CELLS; i += 1024) ((int*)hw)[i] = 0;
    __syncthreads();
    int k0 = woff[w], k1 = woff[w + 1];
    for (int k = k0 + t; k < k1; k += 1024) {
        int r = recs1[k];
        atomicAdd(&degc[((unsigned)r) >> 20], 1);
        atomicAdd(&hw[wid][(r & 0xFFFFF) >> SSH], 1);
    }
    __syncthreads();
    if (t < CELLS) {
        int s = 0;
        for (int q = 0; q < 16; ++q) s += hw[q][t];
        cnt_s[t] = s;
    }
    __syncthreads();
    if (t == 0) {
        int run = k0;
        for (int sb = 0; sb < NSB; ++sb) {
            cur[sb] = run;
            boff[w * CELLS + sb] = run;
            run += cnt_s[sb];
        }
        boff[w * CELLS + NSB] = k1;
    }
    __syncthreads();
    for (int k = k0 + t; k < k1; k += 1024) {
        int r = recs1[k];
        int sb = (r & 0xFFFFF) >> SSH;
        int slot = atomicAdd(&cur[sb], 1);
        recs2[slot] = (int)(((((unsigned)r) >> 20) << SSH) | (unsigned)(r & (SW - 1)));
    }
    // epilogue: deg16 / dinv / v for this window's nodes
    for (int idx = t; idx < DW; idx += 1024) {
        int node = w * DW + idx;
        if (node < N) {
            int d = degc[idx];
            deg16[node] = (unsigned short)d;
            float di = rsqrtf((float)d + 1.0f);
            v[node] = (_Float16)(di * x[node]);
        }
    }
}

// ---- scatter: slice-staged LDS gather + LDS atomic scatter, 2 halves ----
__global__ __launch_bounds__(GTHR) void k_gs(const int* __restrict__ recs2,
                                             const int* __restrict__ boff,
                                             const _Float16* __restrict__ val,
                                             int NSB,
                                             float* __restrict__ accg, int N) {
    __shared__ float acc[DW];                        // 16 KB
    __shared__ __align__(16) _Float16 slice[2][SW];  // 2 x 32 KB
    int t = threadIdx.x;
    int w = blockIdx.x >> 1, h = blockIdx.x & 1;
    int half = (NSB + 1) >> 1;
    int sb0 = h * half;
    int sbN = NSB - sb0 < half ? NSB - sb0 : half;   // slices this half owns
#pragma unroll
    for (int j = 0; j < DW / GTHR; ++j) acc[t + GTHR * j] = 0.0f;

    const vint4* vp = reinterpret_cast<const vint4*>(val);
    vint4 st[4];                                     // SW*2B/16B/GTHR = 4
#pragma unroll
    for (int i = 0; i < 4; ++i) st[i] = vp[(long)sb0 * (SW / 8) + i * GTHR + t];
#pragma unroll
    for (int i = 0; i < 4; ++i) ((vint4*)slice[0])[i * GTHR + t] = st[i];
    int p = 0;
    for (int s = 0; s < sbN; ++s) {
        int sb = sb0 + s;
        if (s + 1 < sbN) {
#pragma unroll
            for (int i = 0; i < 4; ++i)
                st[i] = vp[(long)(sb + 1) * (SW / 8) + i * GTHR + t];
        }
        __syncthreads();                             // slice[p] ready (+ acc zero)
        int k0 = boff[w * CELLS + sb], k1 = boff[w * CELLS + sb + 1];
        const _Float16* sl = slice[p];
        for (int k = k0 + t; k < k1; k += GTHR) {
            int r = __builtin_nontemporal_load(recs2 + k);
            atomicAdd(&acc[((unsigned)r) >> SSH], (float)sl[r & (SW - 1)]);
        }
        if (s + 1 < sbN) {
#pragma unroll
            for (int i = 0; i < 4; ++i) ((vint4*)slice[p ^ 1])[i * GTHR + t] = st[i];
        }
        p ^= 1;
    }
    __syncthreads();
#pragma unroll
    for (int j = 0; j < DW / GTHR; ++j) {
        int idx = t + GTHR * j;
        int node = w * DW + idx;
        float a = acc[idx];
        if (node < N && a != 0.0f) atomicAdd(&accg[node], a);
    }
}

// ---- layer-1 epilogue: fused MLP -> u; re-zeros accg for layer 2 ----
__global__ __launch_bounds__(256) void k_u(float* __restrict__ accg,
                                           const unsigned short* __restrict__ deg16,
                                           const _Float16* __restrict__ v,
                                           const float* __restrict__ W1,
                                           const float* __restrict__ b1,
                                           const float* __restrict__ W2,
                                           _Float16* __restrict__ u, int N) {
    int i = blockIdx.x * blockDim.x + threadIdx.x;
    if (i < N) {
        float di = rsqrtf((float)deg16[i] + 1.0f);
        float at = di * (accg[i] + (float)v[i]);
        accg[i] = 0.0f;
        float ss = 0.0f;
#pragma unroll
        for (int jj = 0; jj < 8; ++jj)
            ss += fmaxf(at * W1[jj] + b1[jj], 0.0f) * W2[jj];
        u[i] = (_Float16)(di * ss);
    }
}

// ---- layer-2 epilogue: finalize ----
__global__ __launch_bounds__(256) void k_out(const float* __restrict__ accg,
                                             const unsigned short* __restrict__ deg16,
                                             const _Float16* __restrict__ u,
                                             const float* __restrict__ b2,
                                             float* __restrict__ out, int N) {
    int i = blockIdx.x * blockDim.x + threadIdx.x;
    if (i < N) {
        float di = rsqrtf((float)deg16[i] + 1.0f);
        out[i] = di * (accg[i] + (float)u[i]) + b2[0];
    }
}

extern "C" void kernel_launch(void* const* d_in, const int* in_sizes, int n_in,
                              void* d_out, int out_size, void* d_ws, size_t ws_size,
                              hipStream_t stream) {
    const float* x  = (const float*)d_in[0];
    const int*   ei = (const int*)d_in[1];   // [2, E] int32
    const float* W1 = (const float*)d_in[2];
    const float* b1 = (const float*)d_in[3];
    const float* W2 = (const float*)d_in[4];
    const float* b2 = (const float*)d_in[5];
    float* out = (float*)d_out;

    int N = in_sizes[0];
    int E = in_sizes[1] / 2;
    const int* src = ei;
    const int* dst = ei + E;

    int NW  = (N + DW - 1) >> DSH;      // dst-windows (245 for N=1e6)
    int NSB = (N + SW - 1) >> SSH;      // src-slices  (62)
    long SPAD = (long)NSB * SW;         // padded value-array length (staging)

    // layout (16B-aligned chunks):
    // accg | wcnt | gcur | woff | boff | deg16 | v | u | recs1 | recs2
    char* w = (char*)d_ws;
    float*          accg  = (float*)w;          w += sizeof(float) * (size_t)N;
    int*            wcnt  = (int*)w;            w += sizeof(int) * (size_t)NW;
    int*            gcur  = (int*)w;            w += sizeof(int) * (size_t)NW;
    int*            woff  = (int*)w;            w += sizeof(int) * (size_t)(NW + 1);
    int*            boff  = (int*)w;            w += sizeof(int) * (size_t)NW * CELLS;
    w = (char*)(((size_t)w + 15) & ~15ul);
    unsigned short* deg16 = (unsigned short*)w; w += sizeof(short) * (size_t)N;
    _Float16*       v     = (_Float16*)w;       w += sizeof(_Float16) * (size_t)SPAD;
    _Float16*       u     = (_Float16*)w;       w += sizeof(_Float16) * (size_t)SPAD;
    int*            recs1 = (int*)w;            w += sizeof(int) * (size_t)E;
    int*            recs2 = (int*)w;

    int NBLK = (E + CHUNK - 1) / CHUNK;
    long zn = (long)N + 2 * NW;          // accg + wcnt + gcur contiguous

    k_zero <<<1024, 256, 0, stream>>>((int*)accg, zn);
    k_wcnt <<<2048, 256, 0, stream>>>(dst, E, NW, wcnt);
    k_wscan<<<1, 256, 0, stream>>>(wcnt, NW, E, woff);
    k_sort1<<<NBLK, STHR, 0, stream>>>(src, dst, E, NW, woff, gcur, recs1);
    k_sort2<<<NW, 1024, 0, stream>>>(recs1, woff, x, NSB, recs2, boff, deg16, v, N);
    k_gs   <<<NW * 2, GTHR, 0, stream>>>(recs2, boff, v, NSB, accg, N);
    k_u    <<<(N + 255) / 256, 256, 0, stream>>>(accg, deg16, v, W1, b1, W2, u, N);
    k_gs   <<<NW * 2, GTHR, 0, stream>>>(recs2, boff, u, NSB, accg, N);
    k_out  <<<(N + 255) / 256, 256, 0, stream>>>(accg, deg16, u, b2, out, N);
}

// Round 7
// 275.233 us; speedup vs baseline: 5.4554x; 1.6013x over previous
//
#include <hip/hip_runtime.h>
#include <math.h>

// GCN 2-layer (1->8->1), collapsed + factored + dst-binned (zero global atomics
// on the accumulate paths).
//
// Math (verified):
//   deg[d]  = #edges into d; dinv = rsqrt(deg+1)            (self-loop)
//   v[i]    = dinv[i]*x[i]                                  (stored fp16)
//   acc1[d] = sum_e v[src[e]]
//   at[i]   = dinv[i]*(acc1[i] + v[i])
//   u[i]    = dinv[i] * sum_j relu(at[i]*W1[j]+b1[j])*W2[j] (stored fp16)
//   out[d]  = dinv[d]*(acc2[d] + u[d]) + b2,  acc2[d] = sum_e u[src[e]]
//
// Round-20: restore the r12 structure (best measured, 279us). Session r14-r19
// calibration: each 10M-edge pass costs ~1cy/lane random LDS read/store,
// ~2-3cy LDS atomic, ~4cy random global gather (L1-fill-limited,
// occupancy-invariant), ~29cy global atomic. The r12 pipeline sits ~5-15%
// above its sum-of-floors; every alternative structure (TLP split, batched
// ILP, two-level LDS-confined, global-atomic scatter) regressed.
// Two zero-risk shavings vs r12:
//   (1) k_sort holds dst quads in REGISTERS across phases A->C (16/thread),
//       eliminating the 64MB phase-C dst re-read (LDS already caps the block
//       at 1/CU, so +16 VGPR is free).
//   (2) k_degv record loads are PLAIN (not NT): no gather to protect there,
//       and recs land in L3 so gs1/gs2's NT reads hit L3 instead of HBM.
// Record = ((dst&2047)<<20)|src (requires N <= 2^20; N = 1e6 here).

typedef int vint4 __attribute__((ext_vector_type(4)));

#define HB    512     // bucket table capacity (>= NB = 489)
#define STHR  1024    // sort block size (16 waves)
#define CHUNK 16384   // edges per sort block (16 edges/thread)
#define BSH   11      // bucket shift (2048 nodes/bucket)
#define BMASK 2047
#define NWIN  2048    // nodes per bucket window

__global__ void k_zero_gcur(int* __restrict__ gcur, int NB) {
    int i = blockIdx.x * blockDim.x + threadIdx.x;
    if (i < NB) gcur[i] = 0;
}

// ---- fused counting sort: one block per 16K-edge chunk ----
__global__ __launch_bounds__(STHR) void k_sort(const int* __restrict__ src,
                                               const int* __restrict__ dst,
                                               int E, int NB, int C,
                                               int* __restrict__ gcur,
                                               int* __restrict__ recs) {
    __shared__ int cnt[HB];            // phase A: counts; phase C: cursors
    __shared__ int off[HB + 4];        // exclusive within-block offsets
    __shared__ int res[HB];            // res2[b] = C*b + gbase[b] - off[b]
    __shared__ int part[STHR];
    __shared__ int stage[CHUNK];       // 64 KB bucket-ordered record staging
    __shared__ unsigned short s2b[CHUNK]; // 32 KB slot -> bucket

    int t = threadIdx.x;
    for (int i = t; i < NB; i += STHR) cnt[i] = 0;
    __syncthreads();

    long s0 = (long)blockIdx.x * CHUNK;
    int end = (int)min((long)CHUNK, (long)E - s0);
    const vint4* pd = reinterpret_cast<const vint4*>(dst + s0);
    const vint4* ps = reinterpret_cast<const vint4*>(src + s0);
    int n4 = end >> 2;

    // ---- phase A: bucket histogram; dst quads stay in REGISTERS for C ----
    vint4 dq[4];
#pragma unroll
    for (int i = 0; i < 4; ++i) {
        int k = t + i * STHR;
        if (k < n4) {
            dq[i] = pd[k];
            atomicAdd(&cnt[((unsigned)dq[i].x) >> BSH], 1);
            atomicAdd(&cnt[((unsigned)dq[i].y) >> BSH], 1);
            atomicAdd(&cnt[((unsigned)dq[i].z) >> BSH], 1);
            atomicAdd(&cnt[((unsigned)dq[i].w) >> BSH], 1);
        }
    }
    for (int k = (n4 << 2) + t; k < end; k += STHR)
        atomicAdd(&cnt[((unsigned)dst[s0 + k]) >> BSH], 1);
    __syncthreads();

    // ---- phase B: block scan (1 bucket/thread; NB <= STHR) + reservation ----
    int c0 = (t < NB) ? cnt[t] : 0;
    part[t] = c0;
    __syncthreads();
    for (int o = 1; o < STHR; o <<= 1) {
        int pv = (t >= o) ? part[t - o] : 0;
        __syncthreads();
        part[t] += pv;
        __syncthreads();
    }
    int base0 = (t > 0) ? part[t - 1] : 0;
    if (t < NB) {
        off[t] = base0;
        cnt[t] = base0;                        // cursor for phase C
        int r0 = c0 ? atomicAdd(&gcur[t], c0) : 0;
        res[t] = t * C + r0 - base0;           // res2
    }
    __syncthreads();

    // ---- phase C: place records into LDS staging (bucket-ordered) ----
#pragma unroll
    for (int i = 0; i < 4; ++i) {
        int k = t + i * STHR;
        if (k < n4) {
            vint4 d = dq[i];
            vint4 s = __builtin_nontemporal_load(ps + k);
            int b, slot;
            b = ((unsigned)d.x) >> BSH; slot = atomicAdd(&cnt[b], 1);
            stage[slot] = ((d.x & BMASK) << 20) | s.x; s2b[slot] = (unsigned short)b;
            b = ((unsigned)d.y) >> BSH; slot = atomicAdd(&cnt[b], 1);
            stage[slot] = ((d.y & BMASK) << 20) | s.y; s2b[slot] = (unsigned short)b;
            b = ((unsigned)d.z) >> BSH; slot = atomicAdd(&cnt[b], 1);
            stage[slot] = ((d.z & BMASK) << 20) | s.z; s2b[slot] = (unsigned short)b;
            b = ((unsigned)d.w) >> BSH; slot = atomicAdd(&cnt[b], 1);
            stage[slot] = ((d.w & BMASK) << 20) | s.w; s2b[slot] = (unsigned short)b;
        }
    }
    for (int k = (n4 << 2) + t; k < end; k += STHR) {
        int d = dst[s0 + k], s = src[s0 + k];
        int b = ((unsigned)d) >> BSH;
        int slot = atomicAdd(&cnt[b], 1);
        stage[slot] = ((d & BMASK) << 20) | s;
        s2b[slot] = (unsigned short)b;
    }
    __syncthreads();

    // ---- phase D: flush; plain store so L2 can merge partial lines ----
    for (int i = t; i < end; i += STHR) {
        int b = s2b[i];
        recs[(long)(res[b] + i)] = stage[i];
    }
}

// ---- per-bucket deg count -> dinv, v(fp16); dual-stream; PLAIN rec loads ----
__global__ __launch_bounds__(512) void k_degv(const int* __restrict__ recs,
                                              const int* __restrict__ gcur, int C,
                                              const float* __restrict__ x,
                                              float* __restrict__ dinv,
                                              _Float16* __restrict__ v, int N) {
    __shared__ int c[NWIN];
    int t = threadIdx.x;
#pragma unroll
    for (int j = 0; j < NWIN / 512; ++j) c[t + 512 * j] = 0;
    __syncthreads();
    long lo = (long)blockIdx.x * C;
    int cnt_ = gcur[blockIdx.x];
    int n4 = cnt_ >> 2;
    const vint4* p = reinterpret_cast<const vint4*>(recs + lo);
    int h4 = (n4 + 1) >> 1;
    for (int k = t; k < h4; k += 512) {
        vint4 ra = p[k];
        int kb = k + h4;
        bool hb = kb < n4;
        vint4 rb = hb ? p[kb] : ra;
        atomicAdd(&c[((unsigned)ra.x) >> 20], 1);
        atomicAdd(&c[((unsigned)ra.y) >> 20], 1);
        atomicAdd(&c[((unsigned)ra.z) >> 20], 1);
        atomicAdd(&c[((unsigned)ra.w) >> 20], 1);
        if (hb) {
            atomicAdd(&c[((unsigned)rb.x) >> 20], 1);
            atomicAdd(&c[((unsigned)rb.y) >> 20], 1);
            atomicAdd(&c[((unsigned)rb.z) >> 20], 1);
            atomicAdd(&c[((unsigned)rb.w) >> 20], 1);
        }
    }
    for (int k = (n4 << 2) + t; k < cnt_; k += 512)
        atomicAdd(&c[((unsigned)recs[lo + k]) >> 20], 1);
    __syncthreads();
#pragma unroll
    for (int j = 0; j < NWIN / 512; ++j) {
        int idx = t + 512 * j;
        int node = blockIdx.x * NWIN + idx;
        if (node < N) {
            float di = rsqrtf((float)c[idx] + 1.0f);
            dinv[node] = di;
            v[node] = (_Float16)(di * x[node]);
        }
    }
}

// ---- layer-1 gather/LDS-scatter + fused MLP -> u(fp16); dual-stream ----
__global__ __launch_bounds__(512) void k_gs1(const int* __restrict__ recs,
                                             const int* __restrict__ gcur, int C,
                                             const _Float16* __restrict__ v,
                                             const float* __restrict__ dinv,
                                             const float* __restrict__ W1,
                                             const float* __restrict__ b1,
                                             const float* __restrict__ W2,
                                             _Float16* __restrict__ u, int N) {
    __shared__ float acc[NWIN];
    int t = threadIdx.x;
#pragma unroll
    for (int j = 0; j < NWIN / 512; ++j) acc[t + 512 * j] = 0.0f;
    __syncthreads();
    long lo = (long)blockIdx.x * C;
    int cnt_ = gcur[blockIdx.x];
    int n4 = cnt_ >> 2;
    const vint4* p = reinterpret_cast<const vint4*>(recs + lo);
    int h4 = (n4 + 1) >> 1;
    for (int k = t; k < h4; k += 512) {
        vint4 ra = __builtin_nontemporal_load(p + k);
        int kb = k + h4;
        bool hb = kb < n4;
        vint4 rb = hb ? __builtin_nontemporal_load(p + kb) : ra;
        float a0 = (float)v[ra.x & 0xFFFFF], a1 = (float)v[ra.y & 0xFFFFF];
        float a2 = (float)v[ra.z & 0xFFFFF], a3 = (float)v[ra.w & 0xFFFFF];
        float g0 = (float)v[rb.x & 0xFFFFF], g1 = (float)v[rb.y & 0xFFFFF];
        float g2 = (float)v[rb.z & 0xFFFFF], g3 = (float)v[rb.w & 0xFFFFF];
        atomicAdd(&acc[((unsigned)ra.x) >> 20], a0);
        atomicAdd(&acc[((unsigned)ra.y) >> 20], a1);
        atomicAdd(&acc[((unsigned)ra.z) >> 20], a2);
        atomicAdd(&acc[((unsigned)ra.w) >> 20], a3);
        if (hb) {
            atomicAdd(&acc[((unsigned)rb.x) >> 20], g0);
            atomicAdd(&acc[((unsigned)rb.y) >> 20], g1);
            atomicAdd(&acc[((unsigned)rb.z) >> 20], g2);
            atomicAdd(&acc[((unsigned)rb.w) >> 20], g3);
        }
    }
    for (int k = (n4 << 2) + t; k < cnt_; k += 512) {
        int r = __builtin_nontemporal_load(recs + lo + k);
        atomicAdd(&acc[((unsigned)r) >> 20], (float)v[r & 0xFFFFF]);
    }
    __syncthreads();
#pragma unroll
    for (int j = 0; j < NWIN / 512; ++j) {
        int idx = t + 512 * j;
        int node = blockIdx.x * NWIN + idx;
        if (node < N) {
            float di = dinv[node];
            float at = di * (acc[idx] + (float)v[node]);
            float s = 0.0f;
#pragma unroll
            for (int jj = 0; jj < 8; ++jj)
                s += fmaxf(at * W1[jj] + b1[jj], 0.0f) * W2[jj];
            u[node] = (_Float16)(di * s);
        }
    }
}

// ---- layer-2 gather/LDS-scatter + fused finalize -> out; dual-stream ----
__global__ __launch_bounds__(512) void k_gs2(const int* __restrict__ recs,
                                             const int* __restrict__ gcur, int C,
                                             const _Float16* __restrict__ u,
                                             const float* __restrict__ dinv,
                                             const float* __restrict__ b2,
                                             float* __restrict__ out, int N) {
    __shared__ float acc[NWIN];
    int t = threadIdx.x;
#pragma unroll
    for (int j = 0; j < NWIN / 512; ++j) acc[t + 512 * j] = 0.0f;
    __syncthreads();
    long lo = (long)blockIdx.x * C;
    int cnt_ = gcur[blockIdx.x];
    int n4 = cnt_ >> 2;
    const vint4* p = reinterpret_cast<const vint4*>(recs + lo);
    int h4 = (n4 + 1) >> 1;
    for (int k = t; k < h4; k += 512) {
        vint4 ra = __builtin_nontemporal_load(p + k);
        int kb = k + h4;
        bool hb = kb < n4;
        vint4 rb = hb ? __builtin_nontemporal_load(p + kb) : ra;
        float a0 = (float)u[ra.x & 0xFFFFF], a1 = (float)u[ra.y & 0xFFFFF];
        float a2 = (float)u[ra.z & 0xFFFFF], a3 = (float)u[ra.w & 0xFFFFF];
        float g0 = (float)u[rb.x & 0xFFFFF], g1 = (float)u[rb.y & 0xFFFFF];
        float g2 = (float)u[rb.z & 0xFFFFF], g3 = (float)u[rb.w & 0xFFFFF];
        atomicAdd(&acc[((unsigned)ra.x) >> 20], a0);
        atomicAdd(&acc[((unsigned)ra.y) >> 20], a1);
        atomicAdd(&acc[((unsigned)ra.z) >> 20], a2);
        atomicAdd(&acc[((unsigned)ra.w) >> 20], a3);
        if (hb) {
            atomicAdd(&acc[((unsigned)rb.x) >> 20], g0);
            atomicAdd(&acc[((unsigned)rb.y) >> 20], g1);
            atomicAdd(&acc[((unsigned)rb.z) >> 20], g2);
            atomicAdd(&acc[((unsigned)rb.w) >> 20], g3);
        }
    }
    for (int k = (n4 << 2) + t; k < cnt_; k += 512) {
        int r = __builtin_nontemporal_load(recs + lo + k);
        atomicAdd(&acc[((unsigned)r) >> 20], (float)u[r & 0xFFFFF]);
    }
    __syncthreads();
#pragma unroll
    for (int j = 0; j < NWIN / 512; ++j) {
        int idx = t + 512 * j;
        int node = blockIdx.x * NWIN + idx;
        if (node < N)
            out[node] = dinv[node] * (acc[idx] + (float)u[node]) + b2[0];
    }
}

extern "C" void kernel_launch(void* const* d_in, const int* in_sizes, int n_in,
                              void* d_out, int out_size, void* d_ws, size_t ws_size,
                              hipStream_t stream) {
    const float* x  = (const float*)d_in[0];
    const int*   ei = (const int*)d_in[1];   // [2, E] int32
    const float* W1 = (const float*)d_in[2];
    const float* b1 = (const float*)d_in[3];
    const float* W2 = (const float*)d_in[4];
    const float* b2 = (const float*)d_in[5];
    float* out = (float*)d_out;

    int N = in_sizes[0];
    int E = in_sizes[1] / 2;
    const int* src = ei;
    const int* dst = ei + E;

    int NB = (N + BMASK) >> BSH;             // 2048-node buckets (489 for N=1e6)

    // fixed bucket capacity: avg + 8 sigma (Poisson), rounded to 64
    int avg = E / NB;
    int C = avg + 8 * (int)sqrt((double)avg) + 64;
    C = (C + 63) & ~63;
    size_t fixed = sizeof(float) * (size_t)N + sizeof(_Float16) * 2ul * N
                 + sizeof(int) * (size_t)NB;
    size_t maxC = (ws_size - fixed) / (sizeof(int) * (size_t)NB);
    if ((size_t)C > maxC) C = (int)maxC;

    char* w = (char*)d_ws;
    float*    dinv = (float*)w;     w += sizeof(float) * (size_t)N;
    _Float16* v    = (_Float16*)w;  w += sizeof(_Float16) * (size_t)N;
    _Float16* u    = (_Float16*)w;  w += sizeof(_Float16) * (size_t)N;
    int*      gcur = (int*)w;       w += sizeof(int) * (size_t)NB;
    int*      recs = (int*)w;       // NB * C ints

    int NBLK = (E + CHUNK - 1) / CHUNK;

    k_zero_gcur<<<(NB + 255) / 256, 256, 0, stream>>>(gcur, NB);
    k_sort<<<NBLK, STHR, 0, stream>>>(src, dst, E, NB, C, gcur, recs);
    k_degv<<<NB, 512, 0, stream>>>(recs, gcur, C, x, dinv, v, N);
    k_gs1 <<<NB, 512, 0, stream>>>(recs, gcur, C, v, dinv, W1, b1, W2, u, N);
    k_gs2 <<<NB, 512, 0, stream>>>(recs, gcur, C, u, dinv, b2, out, N);
}